// Round 5
// baseline (703.584 us; speedup 1.0000x reference)
//
#include <hip/hip_runtime.h>
#include <hip/hip_bf16.h>

typedef __bf16 bf16;
typedef __bf16 bf16x8 __attribute__((ext_vector_type(8)));
typedef float  f32x4  __attribute__((ext_vector_type(4)));
typedef unsigned int uint32;

__device__ __forceinline__ float b2f(bf16 x) { return (float)x; }
__device__ __forceinline__ bf16  f2b(float x) { return (bf16)x; }

// load 8 contiguous elements as bf16x8, converting when source is f32
__device__ __forceinline__ bf16x8 load8(const bf16* p) { return *(const bf16x8*)p; }
__device__ __forceinline__ bf16x8 load8(const float* p) {
  f32x4 a = *(const f32x4*)p;
  f32x4 b = *(const f32x4*)(p + 4);
  bf16x8 r;
#pragma unroll
  for (int j = 0; j < 4; ++j) { r[j] = f2b(a[j]); r[j + 4] = f2b(b[j]); }
  return r;
}

// ---------------------------------------------------------------------------
// window token -> qkv row (spatial) mapping
// wi = ((b*4+dblk)*8+hblk)*8+wblk ; t = td*16+th*4+tw
__device__ __forceinline__ int rowOf(int wi, int t) {
  int bb = wi >> 8, db = (wi >> 6) & 3, hb = (wi >> 3) & 7, wk = wi & 7;
  int z = db * 4 + (t >> 4);
  int y = hb * 4 + ((t >> 2) & 3);
  int x = wk * 4 + (t & 3);
  return ((bb * 16 + z) * 32 + y) * 32 + x;
}

// ---------------------------------------------------------------------------
// Transpose qkv_w [256,768] -> BtQ [768,256] bf16; proj_w [256,256] -> BtP bf16
__global__ __launch_bounds__(256) void transpose_w_kernel(
    const float* __restrict__ qkv_w, const float* __restrict__ proj_w,
    bf16* __restrict__ BtQ, bf16* __restrict__ BtP)
{
  int idx = blockIdx.x * 256 + threadIdx.x;
  if (idx < 768 * 256) {
    int n = idx >> 8, k = idx & 255;
    BtQ[idx] = f2b(qkv_w[k * 768 + n]);
  } else {
    int i2 = idx - 768 * 256;
    int n = i2 >> 8, k = i2 & 255;
    BtP[i2] = f2b(proj_w[k * 256 + n]);
  }
}

// ---------------------------------------------------------------------------
// Weff[g][tap][c3][u] = sum_i dep_w[(g*8+u), i, tap] * fc_w[i, c3]
// wbG[g][tap][u]      = sum_i dep_w[(g*8+u), i, tap] * fc_b[i]
__global__ __launch_bounds__(256) void weff_kernel(
    const float* __restrict__ dep_w, const float* __restrict__ fc_w,
    const float* __restrict__ fc_b, float* __restrict__ Weff, float* __restrict__ wbG)
{
  int tap = blockIdx.x;       // 27
  int g   = blockIdx.y;       // 32
  int u   = threadIdx.x >> 5; // 8
  int c3  = threadIdx.x & 31;
  int oc  = g * 8 + u;
  if (c3 < 24) {
    float s = 0.f;
    for (int i = 0; i < 27; ++i)
      s += dep_w[(oc * 27 + i) * 27 + tap] * fc_w[i * 24 + c3];
    Weff[((g * 27 + tap) * 24 + c3) * 8 + u] = s;
  }
  if (c3 == 0) {
    float s = 0.f;
    for (int i = 0; i < 27; ++i)
      s += dep_w[(oc * 27 + i) * 27 + tap] * fc_b[i];
    wbG[(g * 27 + tap) * 8 + u] = s;
  }
}

// ---------------------------------------------------------------------------
// MFMA GEMM, K=256 fixed, 128x128 tile, 4 waves (2x2), BK=32.
// C[M,N] = A[M,256] * Bt[N,256]^T.
// REMAP=0: plain C store. REMAP=1: +bias, *alpha, window-reverse row remap.
template <int REMAP, typename TA, typename TC>
__global__ __launch_bounds__(256) void gemm_k256(
    const TA* __restrict__ A, const bf16* __restrict__ Bt, TC* __restrict__ C,
    const float* __restrict__ bias, const float* __restrict__ alpha_ptr, int ldc)
{
  __shared__ bf16 As[128 * 32];
  __shared__ bf16 Bs[128 * 32];
  const int tid  = threadIdx.x;
  const int lane = tid & 63;
  const int w    = tid >> 6;
  const int wm   = w >> 1, wn = w & 1;
  const int m0 = blockIdx.x * 128, n0 = blockIdx.y * 128;
  const int lm = lane & 15, lk = (lane >> 4) * 8;
  const int r_ld = tid >> 2;        // 0..63
  const int c_ld = (tid & 3) * 8;   // 0,8,16,24

  const f32x4 vzero = {0.f, 0.f, 0.f, 0.f};
  f32x4 acc[4][4];
  for (int i = 0; i < 4; ++i)
    for (int j = 0; j < 4; ++j) acc[i][j] = vzero;

  for (int k0 = 0; k0 < 256; k0 += 32) {
    __syncthreads();
    {
      bf16x8 a0 = load8(A + (size_t)(m0 + r_ld) * 256 + k0 + c_ld);
      bf16x8 a1 = load8(A + (size_t)(m0 + 64 + r_ld) * 256 + k0 + c_ld);
      bf16x8 b0 = load8(Bt + (size_t)(n0 + r_ld) * 256 + k0 + c_ld);
      bf16x8 b1 = load8(Bt + (size_t)(n0 + 64 + r_ld) * 256 + k0 + c_ld);
      *(bf16x8*)&As[r_ld * 32 + c_ld]        = a0;
      *(bf16x8*)&As[(64 + r_ld) * 32 + c_ld] = a1;
      *(bf16x8*)&Bs[r_ld * 32 + c_ld]        = b0;
      *(bf16x8*)&Bs[(64 + r_ld) * 32 + c_ld] = b1;
    }
    __syncthreads();
    bf16x8 aF[4], bF[4];
#pragma unroll
    for (int fm = 0; fm < 4; ++fm)
      aF[fm] = *(const bf16x8*)&As[(wm * 64 + fm * 16 + lm) * 32 + lk];
#pragma unroll
    for (int fn = 0; fn < 4; ++fn)
      bF[fn] = *(const bf16x8*)&Bs[(wn * 64 + fn * 16 + lm) * 32 + lk];
#pragma unroll
    for (int fm = 0; fm < 4; ++fm)
#pragma unroll
      for (int fn = 0; fn < 4; ++fn)
        acc[fm][fn] = __builtin_amdgcn_mfma_f32_16x16x32_bf16(aF[fm], bF[fn], acc[fm][fn], 0, 0, 0);
  }

  float alphaV = 1.f;
  if (REMAP) alphaV = alpha_ptr[0];
#pragma unroll
  for (int fm = 0; fm < 4; ++fm)
#pragma unroll
    for (int fn = 0; fn < 4; ++fn)
#pragma unroll
      for (int j = 0; j < 4; ++j) {
        int r  = m0 + wm * 64 + fm * 16 + ((lane >> 4) * 4) + j;
        int cc = n0 + wn * 64 + fn * 16 + lm;
        float v = acc[fm][fn][j];
        if constexpr (REMAP) {
          v = (v + bias[cc]) * alphaV;
          int wi = r >> 6, t = r & 63;
          int rp = rowOf(wi, t);
          C[(size_t)rp * 256 + cc] = (TC)v;
        } else {
          C[(size_t)r * ldc + cc] = (TC)v;
        }
      }
}

// ---------------------------------------------------------------------------
// Repack qkv (scrambled f_all view) -> In[b][g=32][c3=24][l=16384]
// In[b][g][c3][l] = qkv_flat_b[c3*524288 + l*32 + g]
__global__ __launch_bounds__(256) void repack_kernel(
    const bf16* __restrict__ qkv, bf16* __restrict__ In)
{
  __shared__ bf16 tl[32][65];
  int lt = blockIdx.x;  // 256 tiles of 64 l
  int c3 = blockIdx.y;  // 24
  int b  = blockIdx.z;  // 4
  int l0 = lt * 64;
  const bf16* src = qkv + (size_t)b * 12582912 + (size_t)c3 * 524288 + (size_t)l0 * 32;
  int tid = threadIdx.x;
  for (int it = 0; it < 8; ++it) {
    int e = it * 256 + tid;
    tl[e & 31][e >> 5] = src[e];
  }
  __syncthreads();
  for (int it = 0; it < 8; ++it) {
    int e = it * 256 + tid;
    int g = e >> 6, l = e & 63;
    In[((size_t)(b * 32 + g) * 24 + c3) * 16384 + l0 + l] = tl[g][l];
  }
}

// ---------------------------------------------------------------------------
// Windowed attention, 1 wave per (window, head). 4 heads per block.
__global__ __launch_bounds__(256) void attn_kernel(
    const bf16* __restrict__ qkv, const float* __restrict__ rpb,
    bf16* __restrict__ attnO)
{
  __shared__ bf16 sm[4][6912];  // per wave: Vt[32][72] then P[64][72]
  int tid = threadIdx.x;
  int w = tid >> 6, lane = tid & 63;
  int h  = blockIdx.y * 4 + w;
  int wi = blockIdx.x;
  int lm = lane & 15, lg = lane >> 4;
  int lk = lg * 8;
  bf16* Vt = &sm[w][0];
  bf16* P  = &sm[w][2304];

  // Q / K fragments directly from global (k-dim = head_dim, contiguous)
  bf16x8 qa[4], kb[4];
#pragma unroll
  for (int fm = 0; fm < 4; ++fm) {
    int t = fm * 16 + lm;
    qa[fm] = *(const bf16x8*)(qkv + (size_t)rowOf(wi, t) * 768 + h * 32 + lk);
  }
#pragma unroll
  for (int fn = 0; fn < 4; ++fn) {
    int t = fn * 16 + lm;
    kb[fn] = *(const bf16x8*)(qkv + (size_t)rowOf(wi, t) * 768 + 256 + h * 32 + lk);
  }
  const f32x4 vzero = {0.f, 0.f, 0.f, 0.f};
  f32x4 acc[4][4];
  for (int i = 0; i < 4; ++i)
    for (int j = 0; j < 4; ++j) acc[i][j] = vzero;
#pragma unroll
  for (int fm = 0; fm < 4; ++fm)
#pragma unroll
    for (int fn = 0; fn < 4; ++fn)
      acc[fm][fn] = __builtin_amdgcn_mfma_f32_16x16x32_bf16(qa[fm], kb[fn], acc[fm][fn], 0, 0, 0);

  // stage V transposed: Vt[e][tok]
  for (int it = 0; it < 32; ++it) {
    int e = it * 64 + lane;
    int tok = e >> 5, ee = e & 31;
    Vt[ee * 72 + tok] = qkv[(size_t)rowOf(wi, tok) * 768 + 512 + h * 32 + ee];
  }

  // softmax in registers; rows live on 16-lane groups
  const float scale = 0.17677669529663687f;  // 32^-0.5
#pragma unroll
  for (int fm = 0; fm < 4; ++fm) {
#pragma unroll
    for (int j = 0; j < 4; ++j) {
      int i  = fm * 16 + lg * 4 + j;
      int di = i >> 4, hi = (i >> 2) & 3, wwi = i & 3;
      float v[4];
      float mx = -1e30f;
#pragma unroll
      for (int fn = 0; fn < 4; ++fn) {
        int jj = fn * 16 + lm;
        int dj = jj >> 4, hj = (jj >> 2) & 3, wj = jj & 3;
        int ridx = (di - dj + 3) * 49 + (hi - hj + 3) * 7 + (wwi - wj + 3);
        float s = acc[fm][fn][j] * scale + rpb[ridx * 8 + h];
        v[fn] = s;
        mx = fmaxf(mx, s);
      }
      for (int sft = 1; sft < 16; sft <<= 1) mx = fmaxf(mx, __shfl_xor(mx, sft));
      float sum = 0.f;
#pragma unroll
      for (int fn = 0; fn < 4; ++fn) { v[fn] = __expf(v[fn] - mx); sum += v[fn]; }
      for (int sft = 1; sft < 16; sft <<= 1) sum += __shfl_xor(sum, sft);
      float inv = 1.f / sum;
#pragma unroll
      for (int fn = 0; fn < 4; ++fn)
        P[i * 72 + fn * 16 + lm] = f2b(v[fn] * inv);
    }
  }
  __syncthreads();  // make cross-lane LDS writes (Vt, P) visible

  // PV: out[64,32] = P[64,64] @ V[64,32]
  f32x4 o[4][2];
  for (int i = 0; i < 4; ++i)
    for (int j = 0; j < 2; ++j) o[i][j] = vzero;
#pragma unroll
  for (int kk = 0; kk < 2; ++kk) {
    bf16x8 pa[4], vb[2];
#pragma unroll
    for (int fm = 0; fm < 4; ++fm)
      pa[fm] = *(const bf16x8*)&P[(fm * 16 + lm) * 72 + kk * 32 + lk];
#pragma unroll
    for (int fn = 0; fn < 2; ++fn)
      vb[fn] = *(const bf16x8*)&Vt[(fn * 16 + lm) * 72 + kk * 32 + lk];
#pragma unroll
    for (int fm = 0; fm < 4; ++fm)
#pragma unroll
      for (int fn = 0; fn < 2; ++fn)
        o[fm][fn] = __builtin_amdgcn_mfma_f32_16x16x32_bf16(pa[fm], vb[fn], o[fm][fn], 0, 0, 0);
  }
#pragma unroll
  for (int fm = 0; fm < 4; ++fm)
#pragma unroll
    for (int fn = 0; fn < 2; ++fn)
#pragma unroll
      for (int j = 0; j < 4; ++j) {
        int i = fm * 16 + lg * 4 + j;
        int e = fn * 16 + lm;
        attnO[((size_t)wi * 64 + i) * 256 + h * 32 + e] = f2b(o[fm][fn][j]);
      }
}

// ---------------------------------------------------------------------------
// Grouped conv (folded 1x1), v3: bf16 LDS tile (25.8 KB total -> 5+ blocks/CU),
// odd-dword row stride (19 dwords) => conflict-free b32/u16 reads and
// lane=row staging writes. Row layout: bf16[38]: data x 0..31, dwords 16..18
// zero (slot 32 = right-halo zero, slot 36 = left-halo zero).
__global__ __launch_bounds__(256, 5) void conv_kernel(
    const bf16* __restrict__ In, const float* __restrict__ Weff,
    const float* __restrict__ wbG, const float* __restrict__ dep_b,
    const float* __restrict__ beta_ptr, float* __restrict__ out)
{
  __shared__ bf16  tile[3][3][34][38];  // 23,256 B
  __shared__ float Ws[3][27][8];        //  2,592 B
  int z = blockIdx.x;  // 16
  int g = blockIdx.y;  // 32
  int b = blockIdx.z;  // 4
  int tid = threadIdx.x;
  int y  = tid >> 3;        // 0..31
  int x0 = (tid & 7) * 4;   // 0..28
  const int liIdx = (x0 == 0) ? 36 : (x0 - 1);  // slot 36 is always 0

  float acc[8][4];
#pragma unroll
  for (int u = 0; u < 8; ++u)
#pragma unroll
    for (int xx = 0; xx < 4; ++xx) acc[u][xx] = 0.f;

  const size_t inBase = (size_t)(b * 32 + g) * 24 * 16384;

  for (int cc = 0; cc < 8; ++cc) {  // 8 chunks of 3 c3
    __syncthreads();
    // ---- stage input tile: 306 rows (c 3 x zz 3 x yy 34), one row/thread ----
#pragma unroll
    for (int rr = 0; rr < 2; ++rr) {
      int row = rr * 256 + tid;
      if (row < 306) {
        int c  = row / 102;
        int r2 = row - c * 102;
        int zz = r2 / 34;
        int yy = r2 - zz * 34;
        int zg = z + zz - 1, yg = yy - 1;
        uint32* dst = (uint32*)&tile[c][zz][yy][0];
        if (zg >= 0 && zg < 16 && yg >= 0 && yg < 32) {
          const bf16* src = In + inBase + (size_t)(cc * 3 + c) * 16384 + zg * 1024 + yg * 32;
#pragma unroll
          for (int q8 = 0; q8 < 4; ++q8) {
            bf16x8 v = *(const bf16x8*)(src + q8 * 8);
            const uint32* pv = (const uint32*)&v;
            dst[q8 * 4 + 0] = pv[0];
            dst[q8 * 4 + 1] = pv[1];
            dst[q8 * 4 + 2] = pv[2];
            dst[q8 * 4 + 3] = pv[3];
          }
        } else {
#pragma unroll
          for (int m = 0; m < 16; ++m) dst[m] = 0u;
        }
        dst[16] = 0u; dst[17] = 0u; dst[18] = 0u;
      }
    }
    // ---- stage weights for this chunk: Ws[c][tap][u] ----
#pragma unroll
    for (int rr = 0; rr < 3; ++rr) {
      int idx = rr * 256 + tid;
      if (idx < 648) {
        int c = idx / 216;
        int r = idx - c * 216;
        int tap = r >> 3, u = r & 7;
        Ws[c][tap][u] = Weff[((size_t)(g * 27 + tap) * 24 + cc * 3 + c) * 8 + u];
      }
    }
    __syncthreads();
    // ---- compute ----
    for (int c = 0; c < 3; ++c) {
#pragma unroll
      for (int kd = 0; kd < 3; ++kd)
#pragma unroll
        for (int kh = 0; kh < 3; ++kh) {
          const bf16* row = &tile[c][kd][y + kh][0];
          uint32 d0 = *(const uint32*)(row + x0);
          uint32 d1 = *(const uint32*)(row + x0 + 2);
          unsigned short eL = *(const unsigned short*)(row + liIdx);
          unsigned short eR = *(const unsigned short*)(row + x0 + 4);
          float in6[6];
          in6[0] = __uint_as_float(((uint32)eL) << 16);
          in6[1] = __uint_as_float(d0 << 16);
          in6[2] = __uint_as_float(d0 & 0xffff0000u);
          in6[3] = __uint_as_float(d1 << 16);
          in6[4] = __uint_as_float(d1 & 0xffff0000u);
          in6[5] = __uint_as_float(((uint32)eR) << 16);
#pragma unroll
          for (int kw = 0; kw < 3; ++kw) {
            const float* wp = &Ws[c][kd * 9 + kh * 3 + kw][0];
            f32x4 w0 = *(const f32x4*)wp;
            f32x4 w1 = *(const f32x4*)(wp + 4);
            float wv[8] = {w0[0], w0[1], w0[2], w0[3], w1[0], w1[1], w1[2], w1[3]};
#pragma unroll
            for (int u = 0; u < 8; ++u) {
              acc[u][0] += wv[u] * in6[kw + 0];
              acc[u][1] += wv[u] * in6[kw + 1];
              acc[u][2] += wv[u] * in6[kw + 2];
              acc[u][3] += wv[u] * in6[kw + 3];
            }
          }
        }
    }
  }

  // fc_b contribution with zero-pad validity + dep_b; RMW into out
  float betaV = beta_ptr[0];
  float wbs[8][4];
#pragma unroll
  for (int u = 0; u < 8; ++u)
#pragma unroll
    for (int xx = 0; xx < 4; ++xx) wbs[u][xx] = 0.f;
  for (int kd = 0; kd < 3; ++kd) {
    int zg = z + kd - 1;
    bool vz = (zg >= 0 && zg < 16);
    for (int kh = 0; kh < 3; ++kh) {
      int yg = y + kh - 1;
      bool vy = (yg >= 0 && yg < 32);
      if (vz && vy)
        for (int kw = 0; kw < 3; ++kw) {
          const float* wbp = wbG + (size_t)(g * 27 + kd * 9 + kh * 3 + kw) * 8;
#pragma unroll
          for (int u = 0; u < 8; ++u) {
            float wv = wbp[u];
#pragma unroll
            for (int xx = 0; xx < 4; ++xx) {
              int xg = x0 + xx + kw - 1;
              if (xg >= 0 && xg < 32) wbs[u][xx] += wv;
            }
          }
        }
    }
  }
  size_t posBase = (size_t)b * 16384 + z * 1024 + y * 32 + x0;
#pragma unroll
  for (int u = 0; u < 8; ++u) {
    int oc = g * 8 + u;
    float db = dep_b[oc];
#pragma unroll
    for (int xx = 0; xx < 4; ++xx) {
      size_t idx = (posBase + xx) * 256 + oc;
      float prev = out[idx];
      out[idx] = prev + betaV * (acc[u][xx] + wbs[u][xx] + db);
    }
  }
}

// ---------------------------------------------------------------------------
extern "C" void kernel_launch(void* const* d_in, const int* in_sizes, int n_in,
                              void* d_out, int out_size, void* d_ws, size_t ws_size,
                              hipStream_t stream)
{
  (void)in_sizes; (void)n_in; (void)out_size; (void)ws_size;
  const float* x_in   = (const float*)d_in[0];
  const float* qkv_w  = (const float*)d_in[1];
  const float* proj_w = (const float*)d_in[2];
  const float* proj_b = (const float*)d_in[3];
  const float* rpb    = (const float*)d_in[4];
  const float* fc_w   = (const float*)d_in[5];
  const float* fc_b   = (const float*)d_in[6];
  const float* dep_w  = (const float*)d_in[7];
  const float* dep_b  = (const float*)d_in[8];
  const float* alpha  = (const float*)d_in[9];
  const float* beta   = (const float*)d_in[10];
  float* out = (float*)d_out;
  char* ws = (char*)d_ws;

  bf16* qkv   = (bf16*)(ws + 0);           // 65536*768  bf16 = 100,663,296 B
  bf16* In    = (bf16*)(ws + 100663296);   // 4*32*24*16384 bf16 = 100,663,296 B
  bf16* attnO = (bf16*)(ws + 201326592);   // 65536*256 bf16 = 33,554,432 B
  bf16* BtQ   = (bf16*)(ws + 234881024);   // 768*256 bf16 = 393,216 B
  bf16* BtP   = (bf16*)(ws + 235274240);   // 256*256 bf16 = 131,072 B
  float* Weff = (float*)(ws + 235405312);  // 32*27*24*8 f32 = 663,552 B
  float* wbG  = (float*)(ws + 236068864);  // 32*27*8 f32 = 27,648 B

  hipLaunchKernelGGL(transpose_w_kernel, dim3(1024), dim3(256), 0, stream,
                     qkv_w, proj_w, BtQ, BtP);
  hipLaunchKernelGGL(weff_kernel, dim3(27, 32), dim3(256), 0, stream,
                     dep_w, fc_w, fc_b, Weff, wbG);
  hipLaunchKernelGGL((gemm_k256<0, float, bf16>), dim3(512, 6), dim3(256), 0, stream,
                     x_in, BtQ, qkv, (const float*)nullptr, (const float*)nullptr, 768);
  hipLaunchKernelGGL(repack_kernel, dim3(256, 24, 4), dim3(256), 0, stream, qkv, In);
  hipLaunchKernelGGL(attn_kernel, dim3(1024, 2), dim3(256), 0, stream, qkv, rpb, attnO);
  hipLaunchKernelGGL((gemm_k256<1, bf16, float>), dim3(512, 2), dim3(256), 0, stream,
                     attnO, BtP, out, proj_b, alpha, 256);
  hipLaunchKernelGGL(conv_kernel, dim3(16, 32, 4), dim3(256), 0, stream,
                     In, Weff, wbG, dep_b, beta, out);
}

// Round 6
// 599.240 us; speedup vs baseline: 1.1741x; 1.1741x over previous
//
#include <hip/hip_runtime.h>
#include <hip/hip_bf16.h>

typedef __bf16 bf16;
typedef __bf16 bf16x8 __attribute__((ext_vector_type(8)));
typedef float  f32x4  __attribute__((ext_vector_type(4)));
typedef unsigned int uint32;

__device__ __forceinline__ float b2f(bf16 x) { return (float)x; }
__device__ __forceinline__ bf16  f2b(float x) { return (bf16)x; }

// load 8 contiguous elements as bf16x8, converting when source is f32
__device__ __forceinline__ bf16x8 load8(const bf16* p) { return *(const bf16x8*)p; }
__device__ __forceinline__ bf16x8 load8(const float* p) {
  f32x4 a = *(const f32x4*)p;
  f32x4 b = *(const f32x4*)(p + 4);
  bf16x8 r;
#pragma unroll
  for (int j = 0; j < 4; ++j) { r[j] = f2b(a[j]); r[j + 4] = f2b(b[j]); }
  return r;
}

// ---------------------------------------------------------------------------
// window token -> qkv row (spatial) mapping
// wi = ((b*4+dblk)*8+hblk)*8+wblk ; t = td*16+th*4+tw
__device__ __forceinline__ int rowOf(int wi, int t) {
  int bb = wi >> 8, db = (wi >> 6) & 3, hb = (wi >> 3) & 7, wk = wi & 7;
  int z = db * 4 + (t >> 4);
  int y = hb * 4 + ((t >> 2) & 3);
  int x = wk * 4 + (t & 3);
  return ((bb * 16 + z) * 32 + y) * 32 + x;
}

// ---------------------------------------------------------------------------
// Transpose qkv_w [256,768] -> BtQ [768,256] bf16; proj_w [256,256] -> BtP bf16
__global__ __launch_bounds__(256) void transpose_w_kernel(
    const float* __restrict__ qkv_w, const float* __restrict__ proj_w,
    bf16* __restrict__ BtQ, bf16* __restrict__ BtP)
{
  int idx = blockIdx.x * 256 + threadIdx.x;
  if (idx < 768 * 256) {
    int n = idx >> 8, k = idx & 255;
    BtQ[idx] = f2b(qkv_w[k * 768 + n]);
  } else {
    int i2 = idx - 768 * 256;
    int n = i2 >> 8, k = i2 & 255;
    BtP[i2] = f2b(proj_w[k * 256 + n]);
  }
}

// ---------------------------------------------------------------------------
// Weff[g][tap][c3][u] = sum_i dep_w[(g*8+u), i, tap] * fc_w[i, c3]
// wbG[g][tap][u]      = sum_i dep_w[(g*8+u), i, tap] * fc_b[i]
__global__ __launch_bounds__(256) void weff_kernel(
    const float* __restrict__ dep_w, const float* __restrict__ fc_w,
    const float* __restrict__ fc_b, float* __restrict__ Weff, float* __restrict__ wbG)
{
  int tap = blockIdx.x;       // 27
  int g   = blockIdx.y;       // 32
  int u   = threadIdx.x >> 5; // 8
  int c3  = threadIdx.x & 31;
  int oc  = g * 8 + u;
  if (c3 < 24) {
    float s = 0.f;
    for (int i = 0; i < 27; ++i)
      s += dep_w[(oc * 27 + i) * 27 + tap] * fc_w[i * 24 + c3];
    Weff[((g * 27 + tap) * 24 + c3) * 8 + u] = s;
  }
  if (c3 == 0) {
    float s = 0.f;
    for (int i = 0; i < 27; ++i)
      s += dep_w[(oc * 27 + i) * 27 + tap] * fc_b[i];
    wbG[(g * 27 + tap) * 8 + u] = s;
  }
}

// ---------------------------------------------------------------------------
// MFMA GEMM, K=256 fixed, 128x128 tile, 4 waves (2x2), BK=32.
// C[M,N] = A[M,256] * Bt[N,256]^T.
// REMAP=0: plain C store. REMAP=1: +bias, *alpha, window-reverse row remap.
template <int REMAP, typename TA, typename TC>
__global__ __launch_bounds__(256) void gemm_k256(
    const TA* __restrict__ A, const bf16* __restrict__ Bt, TC* __restrict__ C,
    const float* __restrict__ bias, const float* __restrict__ alpha_ptr, int ldc)
{
  __shared__ bf16 As[128 * 32];
  __shared__ bf16 Bs[128 * 32];
  const int tid  = threadIdx.x;
  const int lane = tid & 63;
  const int w    = tid >> 6;
  const int wm   = w >> 1, wn = w & 1;
  const int m0 = blockIdx.x * 128, n0 = blockIdx.y * 128;
  const int lm = lane & 15, lk = (lane >> 4) * 8;
  const int r_ld = tid >> 2;        // 0..63
  const int c_ld = (tid & 3) * 8;   // 0,8,16,24

  const f32x4 vzero = {0.f, 0.f, 0.f, 0.f};
  f32x4 acc[4][4];
  for (int i = 0; i < 4; ++i)
    for (int j = 0; j < 4; ++j) acc[i][j] = vzero;

  for (int k0 = 0; k0 < 256; k0 += 32) {
    __syncthreads();
    {
      bf16x8 a0 = load8(A + (size_t)(m0 + r_ld) * 256 + k0 + c_ld);
      bf16x8 a1 = load8(A + (size_t)(m0 + 64 + r_ld) * 256 + k0 + c_ld);
      bf16x8 b0 = load8(Bt + (size_t)(n0 + r_ld) * 256 + k0 + c_ld);
      bf16x8 b1 = load8(Bt + (size_t)(n0 + 64 + r_ld) * 256 + k0 + c_ld);
      *(bf16x8*)&As[r_ld * 32 + c_ld]        = a0;
      *(bf16x8*)&As[(64 + r_ld) * 32 + c_ld] = a1;
      *(bf16x8*)&Bs[r_ld * 32 + c_ld]        = b0;
      *(bf16x8*)&Bs[(64 + r_ld) * 32 + c_ld] = b1;
    }
    __syncthreads();
    bf16x8 aF[4], bF[4];
#pragma unroll
    for (int fm = 0; fm < 4; ++fm)
      aF[fm] = *(const bf16x8*)&As[(wm * 64 + fm * 16 + lm) * 32 + lk];
#pragma unroll
    for (int fn = 0; fn < 4; ++fn)
      bF[fn] = *(const bf16x8*)&Bs[(wn * 64 + fn * 16 + lm) * 32 + lk];
#pragma unroll
    for (int fm = 0; fm < 4; ++fm)
#pragma unroll
      for (int fn = 0; fn < 4; ++fn)
        acc[fm][fn] = __builtin_amdgcn_mfma_f32_16x16x32_bf16(aF[fm], bF[fn], acc[fm][fn], 0, 0, 0);
  }

  float alphaV = 1.f;
  if (REMAP) alphaV = alpha_ptr[0];
#pragma unroll
  for (int fm = 0; fm < 4; ++fm)
#pragma unroll
    for (int fn = 0; fn < 4; ++fn)
#pragma unroll
      for (int j = 0; j < 4; ++j) {
        int r  = m0 + wm * 64 + fm * 16 + ((lane >> 4) * 4) + j;
        int cc = n0 + wn * 64 + fn * 16 + lm;
        float v = acc[fm][fn][j];
        if constexpr (REMAP) {
          v = (v + bias[cc]) * alphaV;
          int wi = r >> 6, t = r & 63;
          int rp = rowOf(wi, t);
          C[(size_t)rp * 256 + cc] = (TC)v;
        } else {
          C[(size_t)r * ldc + cc] = (TC)v;
        }
      }
}

// ---------------------------------------------------------------------------
// Repack qkv (scrambled f_all view) -> In[b][g=32][c3=24][l=16384]
// In[b][g][c3][l] = qkv_flat_b[c3*524288 + l*32 + g]
__global__ __launch_bounds__(256) void repack_kernel(
    const bf16* __restrict__ qkv, bf16* __restrict__ In)
{
  __shared__ bf16 tl[32][65];
  int lt = blockIdx.x;  // 256 tiles of 64 l
  int c3 = blockIdx.y;  // 24
  int b  = blockIdx.z;  // 4
  int l0 = lt * 64;
  const bf16* src = qkv + (size_t)b * 12582912 + (size_t)c3 * 524288 + (size_t)l0 * 32;
  int tid = threadIdx.x;
  for (int it = 0; it < 8; ++it) {
    int e = it * 256 + tid;
    tl[e & 31][e >> 5] = src[e];
  }
  __syncthreads();
  for (int it = 0; it < 8; ++it) {
    int e = it * 256 + tid;
    int g = e >> 6, l = e & 63;
    In[((size_t)(b * 32 + g) * 24 + c3) * 16384 + l0 + l] = tl[g][l];
  }
}

// ---------------------------------------------------------------------------
// Windowed attention, 1 wave per (window, head). 4 heads per block.
__global__ __launch_bounds__(256) void attn_kernel(
    const bf16* __restrict__ qkv, const float* __restrict__ rpb,
    bf16* __restrict__ attnO)
{
  __shared__ bf16 sm[4][6912];  // per wave: Vt[32][72] then P[64][72]
  int tid = threadIdx.x;
  int w = tid >> 6, lane = tid & 63;
  int h  = blockIdx.y * 4 + w;
  int wi = blockIdx.x;
  int lm = lane & 15, lg = lane >> 4;
  int lk = lg * 8;
  bf16* Vt = &sm[w][0];
  bf16* P  = &sm[w][2304];

  // Q / K fragments directly from global (k-dim = head_dim, contiguous)
  bf16x8 qa[4], kb[4];
#pragma unroll
  for (int fm = 0; fm < 4; ++fm) {
    int t = fm * 16 + lm;
    qa[fm] = *(const bf16x8*)(qkv + (size_t)rowOf(wi, t) * 768 + h * 32 + lk);
  }
#pragma unroll
  for (int fn = 0; fn < 4; ++fn) {
    int t = fn * 16 + lm;
    kb[fn] = *(const bf16x8*)(qkv + (size_t)rowOf(wi, t) * 768 + 256 + h * 32 + lk);
  }
  const f32x4 vzero = {0.f, 0.f, 0.f, 0.f};
  f32x4 acc[4][4];
  for (int i = 0; i < 4; ++i)
    for (int j = 0; j < 4; ++j) acc[i][j] = vzero;
#pragma unroll
  for (int fm = 0; fm < 4; ++fm)
#pragma unroll
    for (int fn = 0; fn < 4; ++fn)
      acc[fm][fn] = __builtin_amdgcn_mfma_f32_16x16x32_bf16(qa[fm], kb[fn], acc[fm][fn], 0, 0, 0);

  // stage V transposed: Vt[e][tok]
  for (int it = 0; it < 32; ++it) {
    int e = it * 64 + lane;
    int tok = e >> 5, ee = e & 31;
    Vt[ee * 72 + tok] = qkv[(size_t)rowOf(wi, tok) * 768 + 512 + h * 32 + ee];
  }

  // softmax in registers; rows live on 16-lane groups
  const float scale = 0.17677669529663687f;  // 32^-0.5
#pragma unroll
  for (int fm = 0; fm < 4; ++fm) {
#pragma unroll
    for (int j = 0; j < 4; ++j) {
      int i  = fm * 16 + lg * 4 + j;
      int di = i >> 4, hi = (i >> 2) & 3, wwi = i & 3;
      float v[4];
      float mx = -1e30f;
#pragma unroll
      for (int fn = 0; fn < 4; ++fn) {
        int jj = fn * 16 + lm;
        int dj = jj >> 4, hj = (jj >> 2) & 3, wj = jj & 3;
        int ridx = (di - dj + 3) * 49 + (hi - hj + 3) * 7 + (wwi - wj + 3);
        float s = acc[fm][fn][j] * scale + rpb[ridx * 8 + h];
        v[fn] = s;
        mx = fmaxf(mx, s);
      }
      for (int sft = 1; sft < 16; sft <<= 1) mx = fmaxf(mx, __shfl_xor(mx, sft));
      float sum = 0.f;
#pragma unroll
      for (int fn = 0; fn < 4; ++fn) { v[fn] = __expf(v[fn] - mx); sum += v[fn]; }
      for (int sft = 1; sft < 16; sft <<= 1) sum += __shfl_xor(sum, sft);
      float inv = 1.f / sum;
#pragma unroll
      for (int fn = 0; fn < 4; ++fn)
        P[i * 72 + fn * 16 + lm] = f2b(v[fn] * inv);
    }
  }
  __syncthreads();  // make cross-lane LDS writes (Vt, P) visible

  // PV: out[64,32] = P[64,64] @ V[64,32]
  f32x4 o[4][2];
  for (int i = 0; i < 4; ++i)
    for (int j = 0; j < 2; ++j) o[i][j] = vzero;
#pragma unroll
  for (int kk = 0; kk < 2; ++kk) {
    bf16x8 pa[4], vb[2];
#pragma unroll
    for (int fm = 0; fm < 4; ++fm)
      pa[fm] = *(const bf16x8*)&P[(fm * 16 + lm) * 72 + kk * 32 + lk];
#pragma unroll
    for (int fn = 0; fn < 2; ++fn)
      vb[fn] = *(const bf16x8*)&Vt[(fn * 16 + lm) * 72 + kk * 32 + lk];
#pragma unroll
    for (int fm = 0; fm < 4; ++fm)
#pragma unroll
      for (int fn = 0; fn < 2; ++fn)
        o[fm][fn] = __builtin_amdgcn_mfma_f32_16x16x32_bf16(pa[fm], vb[fn], o[fm][fn], 0, 0, 0);
  }
#pragma unroll
  for (int fm = 0; fm < 4; ++fm)
#pragma unroll
    for (int fn = 0; fn < 2; ++fn)
#pragma unroll
      for (int j = 0; j < 4; ++j) {
        int i = fm * 16 + lg * 4 + j;
        int e = fn * 16 + lm;
        attnO[((size_t)wi * 64 + i) * 256 + h * 32 + e] = f2b(o[fm][fn][j]);
      }
}

// ---------------------------------------------------------------------------
// Grouped conv (folded 1x1), v4: bf16 LDS tile (25.8 KB total), odd-dword row
// stride, launch_bounds(256,4) => VGPR cap 128 (kernel needs ~100, NO spill;
// the (256,5) cap at 48 VGPRs caused 430 MB of scratch traffic in v3).
__global__ __launch_bounds__(256, 4) void conv_kernel(
    const bf16* __restrict__ In, const float* __restrict__ Weff,
    const float* __restrict__ wbG, const float* __restrict__ dep_b,
    const float* __restrict__ beta_ptr, float* __restrict__ out)
{
  __shared__ bf16  tile[3][3][34][38];  // 23,256 B
  __shared__ float Ws[3][27][8];        //  2,592 B
  int z = blockIdx.x;  // 16
  int g = blockIdx.y;  // 32
  int b = blockIdx.z;  // 4
  int tid = threadIdx.x;
  int y  = tid >> 3;        // 0..31
  int x0 = (tid & 7) * 4;   // 0..28
  const int liIdx = (x0 == 0) ? 36 : (x0 - 1);  // slot 36 is always 0

  float acc[8][4];
#pragma unroll
  for (int u = 0; u < 8; ++u)
#pragma unroll
    for (int xx = 0; xx < 4; ++xx) acc[u][xx] = 0.f;

  const size_t inBase = (size_t)(b * 32 + g) * 24 * 16384;

  for (int cc = 0; cc < 8; ++cc) {  // 8 chunks of 3 c3
    __syncthreads();
    // ---- stage input tile: 306 rows (c 3 x zz 3 x yy 34), one row/thread ----
#pragma unroll
    for (int rr = 0; rr < 2; ++rr) {
      int row = rr * 256 + tid;
      if (row < 306) {
        int c  = row / 102;
        int r2 = row - c * 102;
        int zz = r2 / 34;
        int yy = r2 - zz * 34;
        int zg = z + zz - 1, yg = yy - 1;
        uint32* dst = (uint32*)&tile[c][zz][yy][0];
        if (zg >= 0 && zg < 16 && yg >= 0 && yg < 32) {
          const bf16* src = In + inBase + (size_t)(cc * 3 + c) * 16384 + zg * 1024 + yg * 32;
#pragma unroll
          for (int q8 = 0; q8 < 4; ++q8) {
            bf16x8 v = *(const bf16x8*)(src + q8 * 8);
            const uint32* pv = (const uint32*)&v;
            dst[q8 * 4 + 0] = pv[0];
            dst[q8 * 4 + 1] = pv[1];
            dst[q8 * 4 + 2] = pv[2];
            dst[q8 * 4 + 3] = pv[3];
          }
        } else {
#pragma unroll
          for (int m = 0; m < 16; ++m) dst[m] = 0u;
        }
        dst[16] = 0u; dst[17] = 0u; dst[18] = 0u;
      }
    }
    // ---- stage weights for this chunk: Ws[c][tap][u] ----
#pragma unroll
    for (int rr = 0; rr < 3; ++rr) {
      int idx = rr * 256 + tid;
      if (idx < 648) {
        int c = idx / 216;
        int r = idx - c * 216;
        int tap = r >> 3, u = r & 7;
        Ws[c][tap][u] = Weff[((size_t)(g * 27 + tap) * 24 + cc * 3 + c) * 8 + u];
      }
    }
    __syncthreads();
    // ---- compute ----
    for (int c = 0; c < 3; ++c) {
#pragma unroll
      for (int kd = 0; kd < 3; ++kd)
#pragma unroll
        for (int kh = 0; kh < 3; ++kh) {
          const bf16* row = &tile[c][kd][y + kh][0];
          uint32 d0 = *(const uint32*)(row + x0);
          uint32 d1 = *(const uint32*)(row + x0 + 2);
          unsigned short eL = *(const unsigned short*)(row + liIdx);
          unsigned short eR = *(const unsigned short*)(row + x0 + 4);
          float in6[6];
          in6[0] = __uint_as_float(((uint32)eL) << 16);
          in6[1] = __uint_as_float(d0 << 16);
          in6[2] = __uint_as_float(d0 & 0xffff0000u);
          in6[3] = __uint_as_float(d1 << 16);
          in6[4] = __uint_as_float(d1 & 0xffff0000u);
          in6[5] = __uint_as_float(((uint32)eR) << 16);
#pragma unroll
          for (int kw = 0; kw < 3; ++kw) {
            const float* wp = &Ws[c][kd * 9 + kh * 3 + kw][0];
            f32x4 w0 = *(const f32x4*)wp;
            f32x4 w1 = *(const f32x4*)(wp + 4);
            float wv[8] = {w0[0], w0[1], w0[2], w0[3], w1[0], w1[1], w1[2], w1[3]};
#pragma unroll
            for (int u = 0; u < 8; ++u) {
              acc[u][0] += wv[u] * in6[kw + 0];
              acc[u][1] += wv[u] * in6[kw + 1];
              acc[u][2] += wv[u] * in6[kw + 2];
              acc[u][3] += wv[u] * in6[kw + 3];
            }
          }
        }
    }
  }

  // fc_b contribution with zero-pad validity + dep_b; RMW into out
  float betaV = beta_ptr[0];
  float wbs[8][4];
#pragma unroll
  for (int u = 0; u < 8; ++u)
#pragma unroll
    for (int xx = 0; xx < 4; ++xx) wbs[u][xx] = 0.f;
  for (int kd = 0; kd < 3; ++kd) {
    int zg = z + kd - 1;
    bool vz = (zg >= 0 && zg < 16);
    for (int kh = 0; kh < 3; ++kh) {
      int yg = y + kh - 1;
      bool vy = (yg >= 0 && yg < 32);
      if (vz && vy)
        for (int kw = 0; kw < 3; ++kw) {
          const float* wbp = wbG + (size_t)(g * 27 + kd * 9 + kh * 3 + kw) * 8;
#pragma unroll
          for (int u = 0; u < 8; ++u) {
            float wv = wbp[u];
#pragma unroll
            for (int xx = 0; xx < 4; ++xx) {
              int xg = x0 + xx + kw - 1;
              if (xg >= 0 && xg < 32) wbs[u][xx] += wv;
            }
          }
        }
    }
  }
  size_t posBase = (size_t)b * 16384 + z * 1024 + y * 32 + x0;
#pragma unroll
  for (int u = 0; u < 8; ++u) {
    int oc = g * 8 + u;
    float db = dep_b[oc];
#pragma unroll
    for (int xx = 0; xx < 4; ++xx) {
      size_t idx = (posBase + xx) * 256 + oc;
      float prev = out[idx];
      out[idx] = prev + betaV * (acc[u][xx] + wbs[u][xx] + db);
    }
  }
}

// ---------------------------------------------------------------------------
extern "C" void kernel_launch(void* const* d_in, const int* in_sizes, int n_in,
                              void* d_out, int out_size, void* d_ws, size_t ws_size,
                              hipStream_t stream)
{
  (void)in_sizes; (void)n_in; (void)out_size; (void)ws_size;
  const float* x_in   = (const float*)d_in[0];
  const float* qkv_w  = (const float*)d_in[1];
  const float* proj_w = (const float*)d_in[2];
  const float* proj_b = (const float*)d_in[3];
  const float* rpb    = (const float*)d_in[4];
  const float* fc_w   = (const float*)d_in[5];
  const float* fc_b   = (const float*)d_in[6];
  const float* dep_w  = (const float*)d_in[7];
  const float* dep_b  = (const float*)d_in[8];
  const float* alpha  = (const float*)d_in[9];
  const float* beta   = (const float*)d_in[10];
  float* out = (float*)d_out;
  char* ws = (char*)d_ws;

  bf16* qkv   = (bf16*)(ws + 0);           // 65536*768  bf16 = 100,663,296 B
  bf16* In    = (bf16*)(ws + 100663296);   // 4*32*24*16384 bf16 = 100,663,296 B
  bf16* attnO = (bf16*)(ws + 201326592);   // 65536*256 bf16 = 33,554,432 B
  bf16* BtQ   = (bf16*)(ws + 234881024);   // 768*256 bf16 = 393,216 B
  bf16* BtP   = (bf16*)(ws + 235274240);   // 256*256 bf16 = 131,072 B
  float* Weff = (float*)(ws + 235405312);  // 32*27*24*8 f32 = 663,552 B
  float* wbG  = (float*)(ws + 236068864);  // 32*27*8 f32 = 27,648 B

  hipLaunchKernelGGL(transpose_w_kernel, dim3(1024), dim3(256), 0, stream,
                     qkv_w, proj_w, BtQ, BtP);
  hipLaunchKernelGGL(weff_kernel, dim3(27, 32), dim3(256), 0, stream,
                     dep_w, fc_w, fc_b, Weff, wbG);
  hipLaunchKernelGGL((gemm_k256<0, float, bf16>), dim3(512, 6), dim3(256), 0, stream,
                     x_in, BtQ, qkv, (const float*)nullptr, (const float*)nullptr, 768);
  hipLaunchKernelGGL(repack_kernel, dim3(256, 24, 4), dim3(256), 0, stream, qkv, In);
  hipLaunchKernelGGL(attn_kernel, dim3(1024, 2), dim3(256), 0, stream, qkv, rpb, attnO);
  hipLaunchKernelGGL((gemm_k256<1, bf16, float>), dim3(512, 2), dim3(256), 0, stream,
                     attnO, BtP, out, proj_b, alpha, 256);
  hipLaunchKernelGGL(conv_kernel, dim3(16, 32, 4), dim3(256), 0, stream,
                     In, Weff, wbG, dep_b, beta, out);
}